// Round 12
// baseline (2401.252 us; speedup 1.0000x reference)
//
#include <hip/hip_runtime.h>
#include <hip/hip_cooperative_groups.h>
#include <hip/hip_bf16.h>
#include <math.h>

namespace cg = cooperative_groups;

// SeaLiceGLKAN — fp32 in/out. Whole T-loop in ONE cooperative kernel:
// per step: 3×(MFMA hop matvec -> softmax edge aggregate) -> MFMA dense chain
// (p-GEMM, tau/g GEMM, phi-on-the-fly u GEMM) + liquid cell epilogue.
// grid.sync() between phases replaces kernel launches.

constexpr int cB = 2, cT = 4, cN = 10000, cF = 16, cH = 64, cE = 160000, cK = 3;
constexpr int cBN = cB * cN;    // 20000
constexpr int cBNH = cBN * cH;  // 1,280,000
constexpr int NB32 = cBN / 32;  // 625 nodegroups of 32 (exact)

typedef const float* fp;
typedef short short8 __attribute__((ext_vector_type(8)));
typedef float f32x4 __attribute__((ext_vector_type(4)));
typedef unsigned short u16;

__device__ __forceinline__ float wsum(float v) {
#pragma unroll
  for (int o = 1; o < 64; o <<= 1) v += __shfl_xor(v, o, 64);
  return v;
}
__device__ __forceinline__ u16 f2b(float f) {  // fp32 -> bf16 bits (RNE)
  unsigned u = __float_as_uint(f);
  u += 0x7FFFu + ((u >> 16) & 1u);
  return (u16)(u >> 16);
}
__device__ __forceinline__ float b2f(u16 b) { return __uint_as_float(((unsigned)b) << 16); }

// ---------------- CSR build ----------------
__global__ void k_zero_i32(int* p, int n) {
  int i = blockIdx.x * 256 + threadIdx.x;
  if (i < n) p[i] = 0;
}

__global__ void k_count(const int* dst, int* counts) {
  int e = blockIdx.x * 256 + threadIdx.x;
  if (e < cE) atomicAdd(&counts[dst[e]], 1);
}

__global__ void k_scan(const int* counts, int* row_ptr, int* cursor) {
  __shared__ int part[1024];
  int t = threadIdx.x;
  const int CH = (cN + 1023) / 1024;  // 10
  int s = 0;
  for (int i = 0; i < CH; i++) {
    int idx = t * CH + i;
    if (idx < cN) s += counts[idx];
  }
  part[t] = s;
  __syncthreads();
  for (int off = 1; off < 1024; off <<= 1) {
    int v = (t >= off) ? part[t - off] : 0;
    __syncthreads();
    part[t] += v;
    __syncthreads();
  }
  int excl = (t == 0) ? 0 : part[t - 1];
  for (int i = 0; i < CH; i++) {
    int idx = t * CH + i;
    if (idx < cN) {
      row_ptr[idx] = excl;
      cursor[idx] = excl;
      excl += counts[idx];
    }
  }
  if (t == 1023) row_ptr[cN] = part[1023];
}

__global__ void k_scatter(const int* src, const int* dst, fp ea, fp w1, fp b1, fp w2, fp b2,
                          int* cursor, int* esrc, float* gcsr) {
  int e = blockIdx.x * 256 + threadIdx.x;
  if (e >= cE) return;
  float a0 = ea[e * 4 + 0], a1 = ea[e * 4 + 1], a2 = ea[e * 4 + 2], a3 = ea[e * 4 + 3];
  float acc = b2[0];
#pragma unroll
  for (int j = 0; j < 16; j++) {
    float tv = b1[j] + a0 * w1[j] + a1 * w1[16 + j] + a2 * w1[32 + j] + a3 * w1[48 + j];
    acc += tanhf(tv) * w2[j];
  }
  float g = 1.f / (1.f + expf(-acc));
  int p = atomicAdd(&cursor[dst[e]], 1);
  esrc[p] = src[e];
  gcsr[p] = g;
}

__global__ void k_init(float* h, u16* h_bf, fp h0) {
  int i = blockIdx.x * 256 + threadIdx.x;
  if (i < cBNH) {
    float v = h0[i & 63];
    h[i] = v;
    h_bf[i] = f2b(v);
  }
}

// ---------------- weight prepack (col-major bf16, K padded) ----------------
__global__ void k_wpack(fp W_tau, fp W_g, fp W_enc, fp W_lt, fp W_hop, u16* Wtg, u16* Wenc,
                        u16* Wlt, u16* Whop) {
  int i = blockIdx.x * 256 + threadIdx.x;
  if (i < 128 * 160) {
    int col = i / 160, k = i - col * 160;
    float v = 0.f;
    if (k < 133) v = (col < 64) ? W_tau[k * 64 + col] : W_g[k * 64 + (col - 64)];
    Wtg[i] = f2b(v);
  } else if (i < 128 * 160 + 64 * 128) {
    int i2 = i - 128 * 160;
    int col = i2 / 128, k = i2 - col * 128;
    Wenc[i2] = f2b(W_enc[k * 64 + col]);
  } else if (i < 128 * 160 + 64 * 128 + 64 * 64) {
    int i3 = i - 128 * 160 - 64 * 128;
    int col = i3 / 64, k = i3 - col * 64;
    Wlt[i3] = f2b(W_lt[k * 64 + col]);
  } else if (i < 128 * 160 + 64 * 128 + 64 * 64 + 3 * 64 * 64) {
    int i4 = i - 128 * 160 - 64 * 128 - 64 * 64;
    int hop = i4 / 4096, rem = i4 - hop * 4096;
    int col = rem / 64, k = rem - col * 64;
    Whop[i4] = f2b(W_hop[hop * 4096 + k * 64 + col]);
  }
}

// ---------------- fused cooperative pipeline ----------------
struct KP {
  const float* x;
  float* h_nm;
  u16* h_bf;
  u16* cur_bf;
  u16* hw_bf;
  u16* agg_bf;
  float* khsum;
  float* ssrc;
  float* sdst;
  const float* gcsr;
  const int* esrc;
  const int* row_ptr;
  const u16* Wtg;
  const u16* Wenc;
  const u16* Wlt;
  const u16* Whop;
  const float* a_src;
  const float* a_dst;
  const float* b_tau;
  const float* b_g;
  const float* b_enc;
  const float* gamma;
  const float* beta;
  const float* c_enc;
  const float* c_dec;
  const float* W_dec;
  const float* b_dec;
  float* out;
};

// LDS map (20096 B): [0,12800) tz(32x168 bf16,10752)/thw(32x72)/tgu(32x200 bf16) union
//                    [12800,14976) sx fp32 32x17
//                    [14976,16000) redA [8][32]; [16000,17024) redB; [17024,20096) redp [24][32]
__global__ __launch_bounds__(256) void k_fused(KP p) {
  __shared__ __align__(16) char lds[20096];
  u16* tzb = (u16*)lds;
  float* sx = (float*)(lds + 12800);
  float* redA = (float*)(lds + 14976);
  float* redB = (float*)(lds + 16000);
  float* redp = (float*)(lds + 17024);
  int tid = threadIdx.x;
  int w = tid >> 6, lane = tid & 63;
  int quad = lane >> 4, l15 = lane & 15;
  int nl8 = tid >> 3, cg8 = tid & 7;  // node-lane 0..31, col-group 0..7
  int G = gridDim.x;
  cg::grid_group grid = cg::this_grid();

  for (int t = 0; t < cT; t++) {
    for (int k = 0; k < cK; k++) {
      // ======== MAT phase: hw = vin @ Whop_k (MFMA), + attention row-sums ========
      const u16* vin = (k == 0) ? p.h_bf : p.cur_bf;
      const u16* Wh = p.Whop + k * 4096;
      const float* avs = p.a_src + k * 64;
      const float* avd = p.a_dst + k * 64;
      for (int g32 = blockIdx.x; g32 < NB32; g32 += G) {
        int base = g32 * 32;
        f32x4 acc[2];
        acc[0] = (f32x4){0.f, 0.f, 0.f, 0.f};
        acc[1] = acc[0];
#pragma unroll
        for (int ks = 0; ks < 2; ks++) {
          short8 bfr = *(const short8*)(Wh + (16 * w + l15) * 64 + ks * 32 + quad * 8);
#pragma unroll
          for (int mt = 0; mt < 2; mt++) {
            short8 afr =
                *(const short8*)(vin + (size_t)(base + mt * 16 + l15) * 64 + ks * 32 + quad * 8);
            acc[mt] = __builtin_amdgcn_mfma_f32_16x16x32_bf16(afr, bfr, acc[mt], 0, 0, 0);
          }
        }
        int col = 16 * w + l15;
#pragma unroll
        for (int mt = 0; mt < 2; mt++)
#pragma unroll
          for (int r = 0; r < 4; r++) tzb[(mt * 16 + quad * 4 + r) * 72 + col] = f2b(acc[mt][r]);
        __syncthreads();
        float r1 = 0.f, r2 = 0.f;
#pragma unroll
        for (int c = 0; c < 8; c++) {
          float v = b2f(tzb[nl8 * 72 + cg8 * 8 + c]);
          r1 += v * avs[cg8 * 8 + c];
          r2 += v * avd[cg8 * 8 + c];
        }
        redA[cg8 * 32 + nl8] = r1;
        redB[cg8 * 32 + nl8] = r2;
        *(short8*)(p.hw_bf + (size_t)(base + nl8) * 64 + cg8 * 8) =
            *(const short8*)(tzb + nl8 * 72 + cg8 * 8);
        __syncthreads();
        if (cg8 == 0) {
          float s1 = 0.f, s2 = 0.f;
#pragma unroll
          for (int g8 = 0; g8 < 8; g8++) {
            s1 += redA[g8 * 32 + nl8];
            s2 += redB[g8 * 32 + nl8];
          }
          p.ssrc[base + nl8] = s1;
          p.sdst[base + nl8] = s2;
        }
        __syncthreads();
      }
      grid.sync();
      // ======== AGG phase: softmax aggregate (+ larval at k==0), wave = node ========
      for (int u = blockIdx.x * 4 + w; u < cBN; u += G * 4) {
        int b = u / cN, n = u - b * cN;
        int r0 = p.row_ptr[n], r1e = p.row_ptr[n + 1];
        const float* sb = p.ssrc + (size_t)b * cN;
        float sd = p.sdst[u];
        float den = 0.f, num = 0.f, lacc = 0.f;
        const u16* hwb = p.hw_bf + (size_t)b * cN * 64;
        const u16* hb = p.h_bf + (size_t)b * cN * 64;
        for (int e0 = r0; e0 < r1e; e0 += 64) {
          int e = e0 + lane;
          bool vld = e < r1e;
          int s = vld ? p.esrc[e] : 0;
          float g = (k == 0 && vld) ? p.gcsr[e] : 0.f;
          float a = 0.f;
          if (vld) {
            float ev = sb[s] + sd;
            ev = ev > 0.f ? ev : 0.2f * ev;
            a = __expf(ev);  // |ev| small; softmax shift-invariant
          }
          den += a;
          int cnt = min(64, r1e - e0);
          for (int j = 0; j < cnt; j++) {
            int sj = __builtin_amdgcn_readlane(s, j);
            float aj = __uint_as_float(__builtin_amdgcn_readlane(__float_as_uint(a), j));
            num += aj * b2f(hwb[(size_t)sj * 64 + lane]);
            if (k == 0) {
              float gj = __uint_as_float(__builtin_amdgcn_readlane(__float_as_uint(g), j));
              lacc += gj * b2f(hb[(size_t)sj * 64 + lane]);
            }
          }
        }
        den = wsum(den);
        float cv = num / (den + 1e-16f);
        size_t ni = (size_t)u * 64 + lane;
        if (k < 2) p.cur_bf[ni] = f2b(cv);
        if (k == 0) {
          p.khsum[ni] = cv;
          p.agg_bf[ni] = f2b(lacc);
        } else {
          p.khsum[ni] += cv;
        }
      }
      grid.sync();
    }
    // ======== MEGA phase: p-GEMM + tau/g GEMM + u GEMM + cell epilogue ========
    for (int g32 = blockIdx.x; g32 < NB32; g32 += G) {
      int base = g32 * 32;
      // stage sx (x rows) + tz h rows (bf16 copy) + zero K-pad
      for (int i = tid; i < 128; i += 256) {
        int tn = i >> 2, q = i & 3;
        int gn = base + tn;
        int gb = gn / cN, gnn = gn - gb * cN;
        float4 xv = *(const float4*)(p.x + (((size_t)gb * cT + t) * cN + gnn) * cF + q * 4);
        sx[tn * 17 + q * 4 + 0] = xv.x;
        sx[tn * 17 + q * 4 + 1] = xv.y;
        sx[tn * 17 + q * 4 + 2] = xv.z;
        sx[tn * 17 + q * 4 + 3] = xv.w;
        const short8* hs = (const short8*)(p.h_bf + (size_t)gn * 64 + q * 16);
        *(short8*)(tzb + tn * 168 + q * 16) = hs[0];
        *(short8*)(tzb + tn * 168 + q * 16 + 8) = hs[1];
      }
      for (int i = tid; i < 32 * 27; i += 256) {
        int tn = i / 27;
        tzb[tn * 168 + 133 + (i - tn * 27)] = 0;
      }
      __syncthreads();
      // env rows 64..68
      for (int i = tid; i < 160; i += 256) {
        int tn = i / 5, j = i - tn * 5;
        tzb[tn * 168 + 64 + j] = f2b(sx[tn * 17 + 8 + j]);
      }
      // G2: u = phi @ Wenc, phi computed on the fly into A-frags
      float ce[8];
#pragma unroll
      for (int cb = 0; cb < 8; cb++) ce[cb] = p.c_enc[cb];
      float inv_e = 7.f / (ce[7] - ce[0]);
      f32x4 accU[2];
      accU[0] = (f32x4){0.f, 0.f, 0.f, 0.f};
      accU[1] = accU[0];
#pragma unroll
      for (int ks = 0; ks < 4; ks++) {
        short8 bfr = *(const short8*)(p.Wenc + (16 * w + l15) * 128 + ks * 32 + quad * 8);
#pragma unroll
        for (int mt = 0; mt < 2; mt++) {
          float xv = sx[(mt * 16 + l15) * 17 + ks * 4 + quad];
          short8 afr;
#pragma unroll
          for (int j = 0; j < 8; j++) {
            float d = (xv - ce[j]) * inv_e;
            afr[j] = (short)f2b(__expf(-d * d));
          }
          accU[mt] = __builtin_amdgcn_mfma_f32_16x16x32_bf16(afr, bfr, accU[mt], 0, 0, 0);
        }
      }
      // G0: plt = agg @ Wlt (A direct from global bf16) -> p rows into tz
      {
        f32x4 accP[2];
        accP[0] = (f32x4){0.f, 0.f, 0.f, 0.f};
        accP[1] = accP[0];
#pragma unroll
        for (int ks = 0; ks < 2; ks++) {
          short8 bfr = *(const short8*)(p.Wlt + (16 * w + l15) * 64 + ks * 32 + quad * 8);
#pragma unroll
          for (int mt = 0; mt < 2; mt++) {
            short8 afr = *(const short8*)(p.agg_bf + (size_t)(base + mt * 16 + l15) * 64 +
                                          ks * 32 + quad * 8);
            accP[mt] = __builtin_amdgcn_mfma_f32_16x16x32_bf16(afr, bfr, accP[mt], 0, 0, 0);
          }
        }
        int colP = 16 * w + l15;
#pragma unroll
        for (int mt = 0; mt < 2; mt++)
#pragma unroll
          for (int r = 0; r < 4; r++) {
            int nl = mt * 16 + quad * 4 + r;
            int gn = base + nl;
            int bB = gn / cN, nn = gn - bB * cN;
            float deg = (float)(p.row_ptr[nn + 1] - p.row_ptr[nn]);
            float pv = p.khsum[(size_t)gn * 64 + colP] * (1.f / 3.f) + accP[mt][r] / (deg + 1.f);
            tzb[nl * 168 + 69 + colP] = f2b(pv);
          }
      }
      __syncthreads();
      // G1: [tau|g] = z @ Wtg (K=160)
      f32x4 accT[4];
#pragma unroll
      for (int i = 0; i < 4; i++) accT[i] = (f32x4){0.f, 0.f, 0.f, 0.f};
#pragma unroll
      for (int ks = 0; ks < 5; ks++) {
        short8 b0 = *(const short8*)(p.Wtg + (32 * w + l15) * 160 + ks * 32 + quad * 8);
        short8 b1 = *(const short8*)(p.Wtg + (32 * w + 16 + l15) * 160 + ks * 32 + quad * 8);
#pragma unroll
        for (int mt = 0; mt < 2; mt++) {
          short8 afr = *(const short8*)(tzb + (mt * 16 + l15) * 168 + ks * 32 + quad * 8);
          accT[mt * 2 + 0] =
              __builtin_amdgcn_mfma_f32_16x16x32_bf16(afr, b0, accT[mt * 2 + 0], 0, 0, 0);
          accT[mt * 2 + 1] =
              __builtin_amdgcn_mfma_f32_16x16x32_bf16(afr, b1, accT[mt * 2 + 1], 0, 0, 0);
        }
      }
      __syncthreads();  // tz dead; tgu overlay
#pragma unroll
      for (int mt = 0; mt < 2; mt++) {
#pragma unroll
        for (int ntl = 0; ntl < 2; ntl++)
#pragma unroll
          for (int r = 0; r < 4; r++) {
            int nl = mt * 16 + quad * 4 + r;
            tzb[nl * 200 + 32 * w + ntl * 16 + l15] = f2b(accT[mt * 2 + ntl][r]);
          }
#pragma unroll
        for (int r = 0; r < 4; r++) {
          int nl = mt * 16 + quad * 4 + r;
          tzb[nl * 200 + 128 + 16 * w + l15] = f2b(accU[mt][r]);
        }
      }
      __syncthreads();
      // epilogue: thread = (node nl8, col-group cg8 of 8 cols)
      int gn = base + nl8;
      int bb = gn / cN, nn = gn - bb * cN;
      float hv8[8];
      {
        const float4* hp = (const float4*)(p.h_nm + (size_t)gn * 64 + cg8 * 8);
        float4 v0 = hp[0], v1 = hp[1];
        hv8[0] = v0.x; hv8[1] = v0.y; hv8[2] = v0.z; hv8[3] = v0.w;
        hv8[4] = v1.x; hv8[5] = v1.y; hv8[6] = v1.z; hv8[7] = v1.w;
      }
      float a8[8];
      float pm = 0.f;
#pragma unroll
      for (int c = 0; c < 8; c++) {
        int col = cg8 * 8 + c;
        float at = b2f(tzb[nl8 * 200 + col]) + p.b_tau[col];
        float ag = b2f(tzb[nl8 * 200 + 64 + col]) + p.b_g[col];
        float tau = 1.f + 9.f / (1.f + __expf(-at));
        float g = tanhf(ag);
        float vv = hv8[c] + 0.25f * (g - hv8[c]) / tau;
        a8[c] = vv;
        pm += vv;
      }
      redA[cg8 * 32 + nl8] = pm;
      __syncthreads();
      float mu = 0.f;
#pragma unroll
      for (int g8 = 0; g8 < 8; g8++) mu += redA[g8 * 32 + nl8];
      mu *= (1.f / 64.f);
      float pv2 = 0.f;
#pragma unroll
      for (int c = 0; c < 8; c++) {
        float d = a8[c] - mu;
        pv2 += d * d;
      }
      redB[cg8 * 32 + nl8] = pv2;
      __syncthreads();
      float var = 0.f;
#pragma unroll
      for (int g8 = 0; g8 < 8; g8++) var += redB[g8 * 32 + nl8];
      var *= (1.f / 64.f);
      float rstd = rsqrtf(var + 1e-5f);
#pragma unroll
      for (int c = 0; c < 8; c++) {
        int col = cg8 * 8 + c;
        a8[c] = (a8[c] - mu) * rstd * p.gamma[col] + p.beta[col] +
                b2f(tzb[nl8 * 200 + 128 + col]) + p.b_enc[col];
      }
      {
        float4 s0, s1;
        s0.x = a8[0]; s0.y = a8[1]; s0.z = a8[2]; s0.w = a8[3];
        s1.x = a8[4]; s1.y = a8[5]; s1.z = a8[6]; s1.w = a8[7];
        float4* hp = (float4*)(p.h_nm + (size_t)gn * 64 + cg8 * 8);
        hp[0] = s0;
        hp[1] = s1;
        short8 hb8;
#pragma unroll
        for (int c = 0; c < 8; c++) hb8[c] = (short)f2b(a8[c]);
        *(short8*)(p.h_bf + (size_t)gn * 64 + cg8 * 8) = hb8;
      }
      float dc0 = p.c_dec[0], dc7 = p.c_dec[7];
      float inv_d = 7.f / (dc7 - dc0);
      float p0 = 0.f, p1 = 0.f, p2 = 0.f;
#pragma unroll
      for (int c = 0; c < 8; c++) {
#pragma unroll
        for (int j = 0; j < 8; j++) {
          float dd = (a8[c] - p.c_dec[j]) * inv_d;
          float ph = __expf(-dd * dd);
          int bx = ((cg8 * 8 + c) * 8 + j) * 3;
          p0 += ph * p.W_dec[bx];
          p1 += ph * p.W_dec[bx + 1];
          p2 += ph * p.W_dec[bx + 2];
        }
      }
      redp[(cg8 * 3 + 0) * 32 + nl8] = p0;
      redp[(cg8 * 3 + 1) * 32 + nl8] = p1;
      redp[(cg8 * 3 + 2) * 32 + nl8] = p2;
      __syncthreads();
      if (cg8 == 0) {
        float v0 = p.b_dec[0], v1 = p.b_dec[1], v2 = p.b_dec[2];
#pragma unroll
        for (int g8 = 0; g8 < 8; g8++) {
          v0 += redp[(g8 * 3 + 0) * 32 + nl8];
          v1 += redp[(g8 * 3 + 1) * 32 + nl8];
          v2 += redp[(g8 * 3 + 2) * 32 + nl8];
        }
        size_t ob = (((size_t)bb * cT + t) * cN + nn) * 3;
        p.out[ob] = fmaxf(v0, 0.f) + log1pf(expf(-fabsf(v0)));
        p.out[ob + 1] = fmaxf(v1, 0.f) + log1pf(expf(-fabsf(v1)));
        p.out[ob + 2] = fmaxf(v2, 0.f) + log1pf(expf(-fabsf(v2)));
      }
      __syncthreads();
    }
    grid.sync();
  }
}

extern "C" void kernel_launch(void* const* d_in, const int* in_sizes, int n_in, void* d_out,
                              int out_size, void* d_ws, size_t ws_size, hipStream_t stream) {
  fp x = (fp)d_in[0];
  fp edge_attr = (fp)d_in[1];
  fp c_enc = (fp)d_in[2];
  fp W_enc = (fp)d_in[3];
  fp b_enc = (fp)d_in[4];
  fp W_hop = (fp)d_in[5];
  fp a_src = (fp)d_in[6];
  fp a_dst = (fp)d_in[7];
  fp w_lt1 = (fp)d_in[8];
  fp b_lt1 = (fp)d_in[9];
  fp w_lt2 = (fp)d_in[10];
  fp b_lt2 = (fp)d_in[11];
  fp W_lt = (fp)d_in[12];
  fp W_tau = (fp)d_in[13];
  fp b_tau = (fp)d_in[14];
  fp W_g = (fp)d_in[15];
  fp b_g = (fp)d_in[16];
  fp gamma = (fp)d_in[17];
  fp beta = (fp)d_in[18];
  fp c_dec = (fp)d_in[19];
  fp W_dec = (fp)d_in[20];
  fp b_dec = (fp)d_in[21];
  fp h0 = (fp)d_in[22];
  const int* eidx = (const int*)d_in[23];
  const int* esrc_in = eidx;
  const int* edst_in = eidx + cE;

  float* fws = (float*)d_ws;
  float* h_nm = fws;   fws += cBNH;
  float* khsum = fws;  fws += cBNH;
  float* ssrc = fws;   fws += cBN;
  float* sdst = fws;   fws += cBN;
  float* gcsr = fws;   fws += cE;
  u16* h_bf = (u16*)fws;   fws += cBNH / 2;
  u16* hw_bf = (u16*)fws;  fws += cBNH / 2;
  u16* cur_bf = (u16*)fws; fws += cBNH / 2;
  u16* agg_bf = (u16*)fws; fws += cBNH / 2;
  u16* Wtg = (u16*)fws;   fws += (128 * 160) / 2;
  u16* Wenc = (u16*)fws;  fws += (64 * 128) / 2;
  u16* Wlt = (u16*)fws;   fws += (64 * 64) / 2;
  u16* Whop = (u16*)fws;  fws += (3 * 64 * 64) / 2;
  int* iws = (int*)fws;
  int* esrc = iws;    iws += cE;
  int* row_ptr = iws; iws += cN + 1;
  int* cursor = iws;  iws += cN;
  int* counts = iws;  iws += cN;

  k_zero_i32<<<(cN + 255) / 256, 256, 0, stream>>>(counts, cN);
  k_count<<<(cE + 255) / 256, 256, 0, stream>>>(edst_in, counts);
  k_scan<<<1, 1024, 0, stream>>>(counts, row_ptr, cursor);
  k_scatter<<<(cE + 255) / 256, 256, 0, stream>>>(esrc_in, edst_in, edge_attr, w_lt1, b_lt1,
                                                  w_lt2, b_lt2, cursor, esrc, gcsr);
  k_init<<<(cBNH + 255) / 256, 256, 0, stream>>>(h_nm, h_bf, h0);
  int wtot = 128 * 160 + 64 * 128 + 64 * 64 + 3 * 64 * 64;
  k_wpack<<<(wtot + 255) / 256, 256, 0, stream>>>(W_tau, W_g, W_enc, W_lt, W_hop, Wtg, Wenc,
                                                  Wlt, Whop);

  KP kp;
  kp.x = x; kp.h_nm = h_nm; kp.h_bf = h_bf; kp.cur_bf = cur_bf; kp.hw_bf = hw_bf;
  kp.agg_bf = agg_bf; kp.khsum = khsum; kp.ssrc = ssrc; kp.sdst = sdst; kp.gcsr = gcsr;
  kp.esrc = esrc; kp.row_ptr = row_ptr; kp.Wtg = Wtg; kp.Wenc = Wenc; kp.Wlt = Wlt;
  kp.Whop = Whop; kp.a_src = a_src; kp.a_dst = a_dst; kp.b_tau = b_tau; kp.b_g = b_g;
  kp.b_enc = b_enc; kp.gamma = gamma; kp.beta = beta; kp.c_enc = c_enc; kp.c_dec = c_dec;
  kp.W_dec = W_dec; kp.b_dec = b_dec; kp.out = (float*)d_out;

  int nbpc = 0;
  hipOccupancyMaxActiveBlocksPerMultiprocessor(&nbpc, k_fused, 256, 0);
  if (nbpc < 1) nbpc = 1;
  int G = nbpc * 256;  // 256 CUs on MI355X
  if (G > 2048) G = 2048;
  void* args[] = {(void*)&kp};
  hipLaunchCooperativeKernel((const void*)k_fused, dim3(G), dim3(256), args, 0, stream);
}

// Round 13
// 533.020 us; speedup vs baseline: 4.5050x; 4.5050x over previous
//
#include <hip/hip_runtime.h>
#include <hip/hip_bf16.h>
#include <math.h>

// SeaLiceGLKAN — fp32 in/out. R11 multi-kernel structure (cooperative R12 reverted).
// Dense chain = MFMA mega-kernel with fused next-step hop0 matvec tail;
// hop matvec = MFMA bf16; hop aggregate = 2-edges-per-iteration softmax gather.

constexpr int cB = 2, cT = 4, cN = 10000, cF = 16, cH = 64, cE = 160000, cK = 3;
constexpr int cBN = cB * cN;    // 20000
constexpr int cBNH = cBN * cH;  // 1,280,000
constexpr int NBLK = (cBN + 63) / 64;  // 313 nodegroups of 64

typedef const float* fp;
typedef short short8 __attribute__((ext_vector_type(8)));
typedef float f32x4 __attribute__((ext_vector_type(4)));
typedef unsigned short u16;

__device__ __forceinline__ float wsum(float v) {
#pragma unroll
  for (int o = 1; o < 64; o <<= 1) v += __shfl_xor(v, o, 64);
  return v;
}
__device__ __forceinline__ u16 f2b(float f) {  // fp32 -> bf16 bits (RNE)
  unsigned u = __float_as_uint(f);
  u += 0x7FFFu + ((u >> 16) & 1u);
  return (u16)(u >> 16);
}
__device__ __forceinline__ float b2f(u16 b) { return __uint_as_float(((unsigned)b) << 16); }

// ---------------- CSR build ----------------
__global__ void k_zero_i32(int* p, int n) {
  int i = blockIdx.x * 256 + threadIdx.x;
  if (i < n) p[i] = 0;
}

__global__ void k_count(const int* dst, int* counts) {
  int e = blockIdx.x * 256 + threadIdx.x;
  if (e < cE) atomicAdd(&counts[dst[e]], 1);
}

__global__ void k_scan(const int* counts, int* row_ptr, int* cursor) {
  __shared__ int part[1024];
  int t = threadIdx.x;
  const int CH = (cN + 1023) / 1024;  // 10
  int s = 0;
  for (int i = 0; i < CH; i++) {
    int idx = t * CH + i;
    if (idx < cN) s += counts[idx];
  }
  part[t] = s;
  __syncthreads();
  for (int off = 1; off < 1024; off <<= 1) {
    int v = (t >= off) ? part[t - off] : 0;
    __syncthreads();
    part[t] += v;
    __syncthreads();
  }
  int excl = (t == 0) ? 0 : part[t - 1];
  for (int i = 0; i < CH; i++) {
    int idx = t * CH + i;
    if (idx < cN) {
      row_ptr[idx] = excl;
      cursor[idx] = excl;
      excl += counts[idx];
    }
  }
  if (t == 1023) row_ptr[cN] = part[1023];
}

__global__ void k_scatter(const int* src, const int* dst, fp ea, fp w1, fp b1, fp w2, fp b2,
                          int* cursor, int* esrc, float* gcsr) {
  int e = blockIdx.x * 256 + threadIdx.x;
  if (e >= cE) return;
  float a0 = ea[e * 4 + 0], a1 = ea[e * 4 + 1], a2 = ea[e * 4 + 2], a3 = ea[e * 4 + 3];
  float acc = b2[0];
#pragma unroll
  for (int j = 0; j < 16; j++) {
    float tv = b1[j] + a0 * w1[j] + a1 * w1[16 + j] + a2 * w1[32 + j] + a3 * w1[48 + j];
    acc += tanhf(tv) * w2[j];
  }
  float g = 1.f / (1.f + expf(-acc));
  int p = atomicAdd(&cursor[dst[e]], 1);
  esrc[p] = src[e];
  gcsr[p] = g;
}

// ---------------- setup: h init + weight prepack (col-major bf16, K padded) ------------
constexpr int cWTOT = 128 * 160 + 64 * 128 + 64 * 64 + 3 * 64 * 64;  // 45056
__global__ void k_setup(float* h, u16* h_bf, fp h0, fp W_tau, fp W_g, fp W_enc, fp W_lt,
                        fp W_hop, u16* Wtg, u16* Wenc, u16* Wlt, u16* Whop) {
  int i = blockIdx.x * 256 + threadIdx.x;
  if (i < cBNH) {
    float v = h0[i & 63];
    h[i] = v;
    h_bf[i] = f2b(v);
  }
  if (i < 128 * 160) {
    int col = i / 160, k = i - col * 160;
    float v = 0.f;
    if (k < 133) v = (col < 64) ? W_tau[k * 64 + col] : W_g[k * 64 + (col - 64)];
    Wtg[i] = f2b(v);
  } else if (i < 128 * 160 + 64 * 128) {
    int i2 = i - 128 * 160;
    int col = i2 / 128, k = i2 - col * 128;
    Wenc[i2] = f2b(W_enc[k * 64 + col]);
  } else if (i < 128 * 160 + 64 * 128 + 64 * 64) {
    int i3 = i - 128 * 160 - 64 * 128;
    int col = i3 / 64, k = i3 - col * 64;
    Wlt[i3] = f2b(W_lt[k * 64 + col]);
  } else if (i < cWTOT) {
    int i4 = i - 128 * 160 - 64 * 128 - 64 * 64;
    int hop = i4 / 4096, rem = i4 - hop * 4096;
    int col = rem / 64, k = rem - col * 64;
    Whop[i4] = f2b(W_hop[hop * 4096 + k * 64 + col]);
  }
}

// ---------------- hop matvec: MFMA, bf16 in/out ----------------
__global__ __launch_bounds__(256) void k_hop_mat_m(const u16* vin_bf, const u16* Wh, fp avs,
                                                   fp avd, u16* hw_bf, float* ssrc,
                                                   float* sdst) {
  __shared__ u16 tin[64 * 72];
  __shared__ u16 thw[64 * 72];
  __shared__ float red1[4][64], red2[4][64];
  int tid = threadIdx.x, w = tid >> 6, lane = tid & 63;
  int quad = lane >> 4, l15 = lane & 15;
  int base = blockIdx.x * 64;
  {
    int tn = tid >> 2, cs = (tid & 3) * 16;
    int gn = base + tn;
    if (gn >= cBN) gn = cBN - 1;
    const short8* src = (const short8*)(vin_bf + (size_t)gn * 64 + cs);
    *(short8*)(tin + tn * 72 + cs) = src[0];
    *(short8*)(tin + tn * 72 + cs + 8) = src[1];
  }
  __syncthreads();
  f32x4 acc[4];
#pragma unroll
  for (int mt = 0; mt < 4; mt++) acc[mt] = (f32x4){0.f, 0.f, 0.f, 0.f};
#pragma unroll
  for (int ks = 0; ks < 2; ks++) {
    short8 bfr = *(const short8*)(Wh + (16 * w + l15) * 64 + ks * 32 + quad * 8);
#pragma unroll
    for (int mt = 0; mt < 4; mt++) {
      short8 afr = *(const short8*)(tin + (mt * 16 + l15) * 72 + ks * 32 + quad * 8);
      acc[mt] = __builtin_amdgcn_mfma_f32_16x16x32_bf16(afr, bfr, acc[mt], 0, 0, 0);
    }
  }
  int col = 16 * w + l15;
#pragma unroll
  for (int mt = 0; mt < 4; mt++) {
#pragma unroll
    for (int r = 0; r < 4; r++) {
      thw[(mt * 16 + quad * 4 + r) * 72 + col] = f2b(acc[mt][r]);
    }
  }
  __syncthreads();
  {
    float r1 = 0.f, r2 = 0.f;
#pragma unroll
    for (int c = 0; c < 16; c++) {
      float v = b2f(thw[lane * 72 + 16 * w + c]);
      r1 += v * avs[16 * w + c];
      r2 += v * avd[16 * w + c];
    }
    red1[w][lane] = r1;
    red2[w][lane] = r2;
  }
  __syncthreads();
  if (w == 0 && base + lane < cBN) {
    ssrc[base + lane] = red1[0][lane] + red1[1][lane] + red1[2][lane] + red1[3][lane];
    sdst[base + lane] = red2[0][lane] + red2[1][lane] + red2[2][lane] + red2[3][lane];
  }
  {
    int tn = tid >> 2, cs = (tid & 3) * 16;
    int gn = base + tn;
    if (gn < cBN) {
      short8* dst = (short8*)(hw_bf + (size_t)gn * 64 + cs);
      dst[0] = *(const short8*)(thw + tn * 72 + cs);
      dst[1] = *(const short8*)(thw + tn * 72 + cs + 8);
    }
  }
}

// ---------------- hop aggregate: 2 edges/iter, half-wave per edge ----------------
__global__ __launch_bounds__(256) void k_hop_agg(const u16* hw_bf, const float* ssrc,
                                                 const float* sdst, const int* row_ptr,
                                                 const int* esrc, const float* gcsr,
                                                 const u16* h_bf, u16* cur_bf, float* khsum,
                                                 u16* agg_bf, int hop) {
  int w = threadIdx.x >> 6, lane = threadIdx.x & 63;
  int half = lane >> 5, hl = lane & 31;
  int u = blockIdx.x * 4 + w;
  int b = u / cN, n = u - b * cN;
  int r0 = row_ptr[n], r1e = row_ptr[n + 1];
  const float* sb = ssrc + (size_t)b * cN;
  float sd = sdst[u];
  float den = 0.f, num0 = 0.f, num1 = 0.f, la0 = 0.f, la1 = 0.f;
  const u16* hwb = hw_bf + (size_t)b * cN * 64;
  const u16* hb = h_bf + (size_t)b * cN * 64;
  for (int e0 = r0; e0 < r1e; e0 += 64) {
    int e = e0 + lane;
    bool vld = e < r1e;
    int s = vld ? esrc[e] : 0;
    float g = (hop == 0 && vld) ? gcsr[e] : 0.f;
    float a = 0.f;
    if (vld) {
      float ev = sb[s] + sd;
      ev = ev > 0.f ? ev : 0.2f * ev;
      a = __expf(ev);  // |ev| small; softmax shift-invariant
    }
    den += a;
    int cnt = min(64, r1e - e0);
    for (int j = 0; j < cnt; j += 2) {
      int sA = __builtin_amdgcn_readlane(s, j);
      int sB = __builtin_amdgcn_readlane(s, j + 1);  // a=0 pads odd tails
      float aA = __uint_as_float(__builtin_amdgcn_readlane(__float_as_uint(a), j));
      float aB = __uint_as_float(__builtin_amdgcn_readlane(__float_as_uint(a), j + 1));
      int sj = half ? sB : sA;
      float aj = half ? aB : aA;
      unsigned d = *(const unsigned*)(hwb + (size_t)sj * 64 + hl * 2);
      num0 += aj * __uint_as_float(d << 16);
      num1 += aj * __uint_as_float(d & 0xffff0000u);
      if (hop == 0) {
        float gA = __uint_as_float(__builtin_amdgcn_readlane(__float_as_uint(g), j));
        float gB = __uint_as_float(__builtin_amdgcn_readlane(__float_as_uint(g), j + 1));
        float gj = half ? gB : gA;
        unsigned dh = *(const unsigned*)(hb + (size_t)sj * 64 + hl * 2);
        la0 += gj * __uint_as_float(dh << 16);
        la1 += gj * __uint_as_float(dh & 0xffff0000u);
      }
    }
  }
  den = wsum(den);
  num0 += __shfl_xor(num0, 32);
  num1 += __shfl_xor(num1, 32);
  if (hop == 0) {
    la0 += __shfl_xor(la0, 32);
    la1 += __shfl_xor(la1, 32);
  }
  if (half == 0) {
    float inv = 1.f / (den + 1e-16f);
    float c0v = num0 * inv, c1v = num1 * inv;
    size_t ni = (size_t)u * 64 + hl * 2;
    if (hop < 2)
      *(unsigned*)(cur_bf + ni) = ((unsigned)f2b(c1v) << 16) | (unsigned)f2b(c0v);
    float2* kp2 = (float2*)(khsum + ni);
    if (hop == 0) {
      float2 kv;
      kv.x = c0v;
      kv.y = c1v;
      *kp2 = kv;
      *(unsigned*)(agg_bf + ni) = ((unsigned)f2b(la1) << 16) | (unsigned)f2b(la0);
    } else {
      float2 kv = *kp2;
      kv.x += c0v;
      kv.y += c1v;
      *kp2 = kv;
    }
  }
}

// ---------------- MFMA mega-kernel: p-GEMM + tau/g GEMM + u GEMM + cell + next hop0 mat --
__global__ __launch_bounds__(256) void k_mega(fp x, int t, float* h_nm, u16* h_bf,
                                              const float* khsum, const u16* agg_bf,
                                              const int* row_ptr, const u16* Wtg,
                                              const u16* Wenc, const u16* Wlt, const u16* Whop0,
                                              fp avs0, fp avd0, u16* hw_bf, float* ssrc,
                                              float* sdst, fp b_tau, fp b_g, fp b_enc, fp gamma,
                                              fp beta, fp c_enc, fp cdec, fp W_dec, fp b_dec,
                                              float* out) {
  __shared__ __align__(16) char lds[59904];
  u16* tz = (u16*)lds;                  // [64][168] bf16
  u16* tphi = (u16*)(lds + 30720);      // [64][136] bf16
  float* tgu = (float*)lds;             // [64][197] fp32 overlay (after GEMMs)
  u16* tzh = (u16*)lds;                 // [64][72] bf16 (tail overlay)
  u16* thw2 = (u16*)(lds + 10240);      // [64][72] bf16 (tail overlay)
  float* sx = (float*)(lds + 50432);
  float* redm = (float*)(lds + 54784);  // [4][64]
  float* redv = redm + 256;             // [4][64]
  float* redp = redv + 256;             // [4][3][64]
  int tid = threadIdx.x;
  int w = tid >> 6, lane = tid & 63;
  int quad = lane >> 4, l15 = lane & 15;
  int base = blockIdx.x * 64;
  {
    int tn = tid >> 2, f4 = (tid & 3) * 4;
    int gn = base + tn;
    if (gn >= cBN) gn = cBN - 1;
    int gb = gn / cN, gnn = gn - gb * cN;
    float4 xv = *(const float4*)(x + (((size_t)gb * cT + t) * cN + gnn) * cF + f4);
    sx[tn * 17 + f4 + 0] = xv.x;
    sx[tn * 17 + f4 + 1] = xv.y;
    sx[tn * 17 + f4 + 2] = xv.z;
    sx[tn * 17 + f4 + 3] = xv.w;
    int f0 = (tid & 3) * 16;
    const short8* hs = (const short8*)(h_bf + (size_t)gn * 64 + f0);
    *(short8*)(tz + tn * 168 + f0) = hs[0];
    *(short8*)(tz + tn * 168 + f0 + 8) = hs[1];
  }
  for (int i = tid; i < 64 * 27; i += 256) {
    int nn2 = i / 27;
    tz[nn2 * 168 + 133 + (i - nn2 * 27)] = 0;
  }
  __syncthreads();
  for (int i = tid; i < 320; i += 256) {
    int j = i >> 6, n2 = i & 63;
    tz[n2 * 168 + 64 + j] = f2b(sx[n2 * 17 + 8 + j]);
  }
  {
    float ec0 = c_enc[0], ec7 = c_enc[7];
    float inv_e = 7.f / (ec7 - ec0);
    for (int i = tid; i < 64 * 128; i += 256) {
      int n2 = i >> 7, j = i & 127;
      int f = j >> 3, cb = j & 7;
      float d = (sx[n2 * 17 + f] - c_enc[cb]) * inv_e;
      tphi[n2 * 136 + j] = f2b(__expf(-d * d));
    }
  }
  __syncthreads();
  // G2: u = phi @ Wenc
  f32x4 accU[4];
#pragma unroll
  for (int mt = 0; mt < 4; mt++) accU[mt] = (f32x4){0.f, 0.f, 0.f, 0.f};
#pragma unroll
  for (int ks = 0; ks < 4; ks++) {
    short8 bfr = *(const short8*)(Wenc + (16 * w + l15) * 128 + ks * 32 + quad * 8);
#pragma unroll
    for (int mt = 0; mt < 4; mt++) {
      short8 afr = *(const short8*)(tphi + (mt * 16 + l15) * 136 + ks * 32 + quad * 8);
      accU[mt] = __builtin_amdgcn_mfma_f32_16x16x32_bf16(afr, bfr, accU[mt], 0, 0, 0);
    }
  }
  // G0: plt = agg @ Wlt (A direct from global bf16 node-major) -> p rows into tz
  {
    f32x4 accP[4];
#pragma unroll
    for (int mt = 0; mt < 4; mt++) accP[mt] = (f32x4){0.f, 0.f, 0.f, 0.f};
#pragma unroll
    for (int ks = 0; ks < 2; ks++) {
      short8 bfr = *(const short8*)(Wlt + (16 * w + l15) * 64 + ks * 32 + quad * 8);
#pragma unroll
      for (int mt = 0; mt < 4; mt++) {
        int gn = base + mt * 16 + l15;
        if (gn >= cBN) gn = cBN - 1;
        short8 afr = *(const short8*)(agg_bf + (size_t)gn * 64 + ks * 32 + quad * 8);
        accP[mt] = __builtin_amdgcn_mfma_f32_16x16x32_bf16(afr, bfr, accP[mt], 0, 0, 0);
      }
    }
    int colP = 16 * w + l15;
#pragma unroll
    for (int mt = 0; mt < 4; mt++) {
#pragma unroll
      for (int r = 0; r < 4; r++) {
        int nl = mt * 16 + quad * 4 + r;
        int gn = base + nl;
        int gnc = gn < cBN ? gn : cBN - 1;
        int bB = gnc / cN, nn = gnc - bB * cN;
        float deg = (float)(row_ptr[nn + 1] - row_ptr[nn]);
        float pv = khsum[(size_t)gnc * 64 + colP] * (1.f / 3.f) + accP[mt][r] / (deg + 1.f);
        tz[nl * 168 + 69 + colP] = f2b(pv);
      }
    }
  }
  __syncthreads();
  // G1: [tau|g] = z @ Wtg (K=160)
  f32x4 accT[8];
#pragma unroll
  for (int i = 0; i < 8; i++) accT[i] = (f32x4){0.f, 0.f, 0.f, 0.f};
#pragma unroll
  for (int ks = 0; ks < 5; ks++) {
    short8 b0 = *(const short8*)(Wtg + (32 * w + l15) * 160 + ks * 32 + quad * 8);
    short8 b1 = *(const short8*)(Wtg + (32 * w + 16 + l15) * 160 + ks * 32 + quad * 8);
#pragma unroll
    for (int mt = 0; mt < 4; mt++) {
      short8 afr = *(const short8*)(tz + (mt * 16 + l15) * 168 + ks * 32 + quad * 8);
      accT[mt * 2 + 0] =
          __builtin_amdgcn_mfma_f32_16x16x32_bf16(afr, b0, accT[mt * 2 + 0], 0, 0, 0);
      accT[mt * 2 + 1] =
          __builtin_amdgcn_mfma_f32_16x16x32_bf16(afr, b1, accT[mt * 2 + 1], 0, 0, 0);
    }
  }
  __syncthreads();  // tz dead; tgu overlay
#pragma unroll
  for (int mt = 0; mt < 4; mt++) {
#pragma unroll
    for (int ntl = 0; ntl < 2; ntl++) {
#pragma unroll
      for (int r = 0; r < 4; r++) {
        int nl = mt * 16 + quad * 4 + r;
        tgu[nl * 197 + 32 * w + ntl * 16 + l15] = accT[mt * 2 + ntl][r];
      }
    }
#pragma unroll
    for (int r = 0; r < 4; r++) {
      int nl = mt * 16 + quad * 4 + r;
      tgu[nl * 197 + 128 + 16 * w + l15] = accU[mt][r];
    }
  }
  __syncthreads();
  // epilogue: thread = node lane, col chunk c0
  int c0 = __builtin_amdgcn_readfirstlane(w * 16);
  int node = base + lane;
  int ngc = node < cBN ? node : cBN - 1;
  int bb = ngc / cN, nn = ngc - bb * cN;
  float hv[16];
  {
    const float4* hp = (const float4*)(h_nm + (size_t)ngc * 64 + c0);
#pragma unroll
    for (int q = 0; q < 4; q++) {
      float4 v = hp[q];
      hv[q * 4 + 0] = v.x; hv[q * 4 + 1] = v.y; hv[q * 4 + 2] = v.z; hv[q * 4 + 3] = v.w;
    }
  }
  float acc[16];
  float pm = 0.f;
#pragma unroll
  for (int c = 0; c < 16; c++) {
    float at = tgu[lane * 197 + c0 + c] + b_tau[c0 + c];
    float ag = tgu[lane * 197 + 64 + c0 + c] + b_g[c0 + c];
    float tau = 1.f + 9.f / (1.f + __expf(-at));
    float g = tanhf(ag);
    float v = hv[c] + 0.25f * (g - hv[c]) / tau;
    acc[c] = v;
    pm += v;
  }
  redm[w * 64 + lane] = pm;
  __syncthreads();
  float mu = (redm[lane] + redm[64 + lane] + redm[128 + lane] + redm[192 + lane]) * (1.f / 64.f);
  float pv = 0.f;
#pragma unroll
  for (int c = 0; c < 16; c++) {
    float d = acc[c] - mu;
    pv += d * d;
  }
  redv[w * 64 + lane] = pv;
  __syncthreads();
  float var = (redv[lane] + redv[64 + lane] + redv[128 + lane] + redv[192 + lane]) * (1.f / 64.f);
  float rstd = rsqrtf(var + 1e-5f);
#pragma unroll
  for (int c = 0; c < 16; c++) {
    acc[c] = (acc[c] - mu) * rstd * gamma[c0 + c] + beta[c0 + c] +
             tgu[lane * 197 + 128 + c0 + c] + b_enc[c0 + c];
  }
  if (node < cBN) {
    float4* hp = (float4*)(h_nm + (size_t)ngc * 64 + c0);
#pragma unroll
    for (int q = 0; q < 4; q++) {
      float4 v;
      v.x = acc[q * 4 + 0]; v.y = acc[q * 4 + 1]; v.z = acc[q * 4 + 2]; v.w = acc[q * 4 + 3];
      hp[q] = v;
    }
    unsigned* bp = (unsigned*)(h_bf + (size_t)ngc * 64 + c0);
#pragma unroll
    for (int q = 0; q < 8; q++) {
      unsigned lo = f2b(acc[q * 2 + 0]);
      unsigned hi = f2b(acc[q * 2 + 1]);
      bp[q] = (hi << 16) | lo;
    }
  }
  // decoder fastkan + softplus
  float dc0 = cdec[0], dc7 = cdec[7];
  float inv_d = 7.f / (dc7 - dc0);
  float p0 = 0.f, p1 = 0.f, p2 = 0.f;
#pragma unroll
  for (int c = 0; c < 16; c++) {
#pragma unroll
    for (int j = 0; j < 8; j++) {
      float dd = (acc[c] - cdec[j]) * inv_d;
      float ph = __expf(-dd * dd);
      int bx = ((c0 + c) * 8 + j) * 3;
      p0 += ph * W_dec[bx];
      p1 += ph * W_dec[bx + 1];
      p2 += ph * W_dec[bx + 2];
    }
  }
  redp[(w * 3 + 0) * 64 + lane] = p0;
  redp[(w * 3 + 1) * 64 + lane] = p1;
  redp[(w * 3 + 2) * 64 + lane] = p2;
  __syncthreads();  // also: all tgu reads complete -> tail overlay safe
  if (w == 0 && node < cBN) {
    float v0 = redp[0 * 64 + lane] + redp[3 * 64 + lane] + redp[6 * 64 + lane] +
               redp[9 * 64 + lane] + b_dec[0];
    float v1 = redp[1 * 64 + lane] + redp[4 * 64 + lane] + redp[7 * 64 + lane] +
               redp[10 * 64 + lane] + b_dec[1];
    float v2 = redp[2 * 64 + lane] + redp[5 * 64 + lane] + redp[8 * 64 + lane] +
               redp[11 * 64 + lane] + b_dec[2];
    size_t ob = (((size_t)bb * cT + t) * cN + nn) * 3;
    out[ob] = fmaxf(v0, 0.f) + log1pf(expf(-fabsf(v0)));
    out[ob + 1] = fmaxf(v1, 0.f) + log1pf(expf(-fabsf(v1)));
    out[ob + 2] = fmaxf(v2, 0.f) + log1pf(expf(-fabsf(v2)));
  }
  // ---- fused tail: next-step hop0 matvec (node-local: uses just-computed h) ----
#pragma unroll
  for (int c = 0; c < 16; c++) tzh[lane * 72 + c0 + c] = f2b(acc[c]);
  __syncthreads();
  f32x4 hacc[4];
#pragma unroll
  for (int mt = 0; mt < 4; mt++) hacc[mt] = (f32x4){0.f, 0.f, 0.f, 0.f};
#pragma unroll
  for (int ks = 0; ks < 2; ks++) {
    short8 bfr = *(const short8*)(Whop0 + (16 * w + l15) * 64 + ks * 32 + quad * 8);
#pragma unroll
    for (int mt = 0; mt < 4; mt++) {
      short8 afr = *(const short8*)(tzh + (mt * 16 + l15) * 72 + ks * 32 + quad * 8);
      hacc[mt] = __builtin_amdgcn_mfma_f32_16x16x32_bf16(afr, bfr, hacc[mt], 0, 0, 0);
    }
  }
  int colh = 16 * w + l15;
#pragma unroll
  for (int mt = 0; mt < 4; mt++) {
#pragma unroll
    for (int r = 0; r < 4; r++) {
      thw2[(mt * 16 + quad * 4 + r) * 72 + colh] = f2b(hacc[mt][r]);
    }
  }
  __syncthreads();
  {
    float r1 = 0.f, r2 = 0.f;
#pragma unroll
    for (int c = 0; c < 16; c++) {
      float v = b2f(thw2[lane * 72 + 16 * w + c]);
      r1 += v * avs0[16 * w + c];
      r2 += v * avd0[16 * w + c];
    }
    redm[w * 64 + lane] = r1;
    redv[w * 64 + lane] = r2;
  }
  __syncthreads();
  if (w == 0 && node < cBN) {
    ssrc[node] = redm[lane] + redm[64 + lane] + redm[128 + lane] + redm[192 + lane];
    sdst[node] = redv[lane] + redv[64 + lane] + redv[128 + lane] + redv[192 + lane];
  }
  {
    int tn = tid >> 2, cs = (tid & 3) * 16;
    int gn = base + tn;
    if (gn < cBN) {
      short8* dst = (short8*)(hw_bf + (size_t)gn * 64 + cs);
      dst[0] = *(const short8*)(thw2 + tn * 72 + cs);
      dst[1] = *(const short8*)(thw2 + tn * 72 + cs + 8);
    }
  }
}

extern "C" void kernel_launch(void* const* d_in, const int* in_sizes, int n_in, void* d_out,
                              int out_size, void* d_ws, size_t ws_size, hipStream_t stream) {
  fp x = (fp)d_in[0];
  fp edge_attr = (fp)d_in[1];
  fp c_enc = (fp)d_in[2];
  fp W_enc = (fp)d_in[3];
  fp b_enc = (fp)d_in[4];
  fp W_hop = (fp)d_in[5];
  fp a_src = (fp)d_in[6];
  fp a_dst = (fp)d_in[7];
  fp w_lt1 = (fp)d_in[8];
  fp b_lt1 = (fp)d_in[9];
  fp w_lt2 = (fp)d_in[10];
  fp b_lt2 = (fp)d_in[11];
  fp W_lt = (fp)d_in[12];
  fp W_tau = (fp)d_in[13];
  fp b_tau = (fp)d_in[14];
  fp W_g = (fp)d_in[15];
  fp b_g = (fp)d_in[16];
  fp gamma = (fp)d_in[17];
  fp beta = (fp)d_in[18];
  fp c_dec = (fp)d_in[19];
  fp W_dec = (fp)d_in[20];
  fp b_dec = (fp)d_in[21];
  fp h0 = (fp)d_in[22];
  const int* eidx = (const int*)d_in[23];
  const int* esrc_in = eidx;
  const int* edst_in = eidx + cE;

  float* fws = (float*)d_ws;
  float* h_nm = fws;   fws += cBNH;
  float* khsum = fws;  fws += cBNH;
  float* ssrc = fws;   fws += cBN;
  float* sdst = fws;   fws += cBN;
  float* gcsr = fws;   fws += cE;
  u16* h_bf = (u16*)fws;   fws += cBNH / 2;
  u16* hw_bf = (u16*)fws;  fws += cBNH / 2;
  u16* cur_bf = (u16*)fws; fws += cBNH / 2;
  u16* agg_bf = (u16*)fws; fws += cBNH / 2;
  u16* Wtg = (u16*)fws;   fws += (128 * 160) / 2;
  u16* Wenc = (u16*)fws;  fws += (64 * 128) / 2;
  u16* Wlt = (u16*)fws;   fws += (64 * 64) / 2;
  u16* Whop = (u16*)fws;  fws += (3 * 64 * 64) / 2;
  int* iws = (int*)fws;
  int* esrc = iws;    iws += cE;
  int* row_ptr = iws; iws += cN + 1;
  int* cursor = iws;  iws += cN;
  int* counts = iws;  iws += cN;

  k_zero_i32<<<(cN + 255) / 256, 256, 0, stream>>>(counts, cN);
  k_count<<<(cE + 255) / 256, 256, 0, stream>>>(edst_in, counts);
  k_scan<<<1, 1024, 0, stream>>>(counts, row_ptr, cursor);
  k_scatter<<<(cE + 255) / 256, 256, 0, stream>>>(esrc_in, edst_in, edge_attr, w_lt1, b_lt1,
                                                  w_lt2, b_lt2, cursor, esrc, gcsr);
  k_setup<<<(cBNH + 255) / 256, 256, 0, stream>>>(h_nm, h_bf, h0, W_tau, W_g, W_enc, W_lt,
                                                  W_hop, Wtg, Wenc, Wlt, Whop);
  // initial hop0 matvec for t=0 (later steps get it fused into k_mega's tail)
  k_hop_mat_m<<<NBLK, 256, 0, stream>>>(h_bf, Whop, a_src, a_dst, hw_bf, ssrc, sdst);

  for (int t = 0; t < cT; t++) {
    for (int k = 0; k < cK; k++) {
      if (k > 0) {
        k_hop_mat_m<<<NBLK, 256, 0, stream>>>(cur_bf, Whop + k * 4096, a_src + k * cH,
                                              a_dst + k * cH, hw_bf, ssrc, sdst);
      }
      k_hop_agg<<<cBN / 4, 256, 0, stream>>>(hw_bf, ssrc, sdst, row_ptr, esrc, gcsr, h_bf,
                                             cur_bf, khsum, agg_bf, k);
    }
    k_mega<<<NBLK, 256, 0, stream>>>(x, t, h_nm, h_bf, khsum, agg_bf, row_ptr, Wtg, Wenc, Wlt,
                                     Whop, a_src, a_dst, hw_bf, ssrc, sdst, b_tau, b_g, b_enc,
                                     gamma, beta, c_enc, c_dec, W_dec, b_dec, (float*)d_out);
  }
}